// Round 6
// baseline (1981.728 us; speedup 1.0000x reference)
//
#include <hip/hip_runtime.h>

// Autoregressive masked net sampler, restructured:
//  - output col i == sampling-time x[:,i]  (masks: out i depends on spins < i only)
//  - spin blocks of KB=8: history part = dense GEMM (MFMA f16, masks all-ones there),
//    intra-block part = sequential per-row (rows independent -> no grid sync)
// R5 lesson: runtime-trip inner loops -> serial load-use per chunk (~5600 cyc/layer
// step). R6: ALL inner trip counts compile-time (masked weights make padded terms
// zero) -> full unroll, loads bulk-issue, one latency exposure per layer.

#define NS   64          // spins
#define HC   20          // hidden channels per spin
#define HTOT 1280        // NS*HC
#define NB   16384       // batch
#define KB   8           // spins per block (8 blocks)
#define BT   8           // batch rows per seq workgroup (single wave: 8 x 8)
#define W6R  80          // W6p padded rows (64 + 16 zero pad for MFMA tile)

typedef _Float16 f16;
typedef _Float16 f16x2 __attribute__((ext_vector_type(2)));
typedef _Float16 f16x8 __attribute__((ext_vector_type(8)));
typedef float f32x4 __attribute__((ext_vector_type(4)));

static __device__ __forceinline__ float dot2f(f16x2 a, f16x2 b, float c) {
#if __has_builtin(__builtin_amdgcn_fdot2)
  return __builtin_amdgcn_fdot2(a, b, c, false);
#else
  return c + (float)a[0] * (float)b[0] + (float)a[1] * (float)b[1];
#endif
}

static __device__ __forceinline__ float dot8f(f16x8 a, f16x8 b, float c) {
  f16x2 a0 = {a[0], a[1]}, a1 = {a[2], a[3]}, a2 = {a[4], a[5]}, a3 = {a[6], a[7]};
  f16x2 b0 = {b[0], b[1]}, b1 = {b[2], b[3]}, b2 = {b[4], b[5]}, b3 = {b[6], b[7]};
  c = dot2f(a0, b0, c);
  c = dot2f(a1, b1, c);
  c = dot2f(a2, b2, c);
  c = dot2f(a3, b3, c);
  return c;
}

static __device__ __forceinline__ float sigm(float z) {
  return __builtin_amdgcn_rcpf(1.0f + __expf(-z));
}

// ---------------------------------------------------------------------------
// prep: build masked, spin-major-permuted f16 weights.
//  Wp [L=0..3][cp][xp]  cp = j_out*20+ch_out, xp = j_in*20+ch_in, mask j_in <= j_out
//  W1p[cp][j_in]        mask j_in <  j_out  (exclusive)
//  W6p[i][xp]           mask j_in <= i  (rows 64..79 zero pad)
// ---------------------------------------------------------------------------
__global__ __launch_bounds__(256) void prep(
    const float* __restrict__ W1, const float* __restrict__ W2,
    const float* __restrict__ W3, const float* __restrict__ W4,
    const float* __restrict__ W5, const float* __restrict__ W6,
    f16* __restrict__ Wp, f16* __restrict__ W1p, f16* __restrict__ W6p) {
  __shared__ float row[HTOT];
  int bid = blockIdx.x;
  if (bid < 4 * HTOT) {
    int L = bid / HTOT, cp = bid % HTOT;
    int j_o = cp / HC, ch_o = cp % HC;
    const float* Wsrc = (L == 0) ? W2 : (L == 1) ? W3 : (L == 2) ? W4 : W5;
    const float* src = Wsrc + (size_t)(ch_o * NS + j_o) * HTOT;
    for (int k = threadIdx.x; k < HTOT; k += 256) row[k] = src[k];
    __syncthreads();
    f16* dst = Wp + (size_t)bid * HTOT;
    for (int xp = threadIdx.x; xp < HTOT; xp += 256) {
      int j_i = xp / HC, ch_i = xp % HC;
      float v = (j_i <= j_o) ? row[ch_i * NS + j_i] : 0.0f;
      dst[xp] = (f16)v;
    }
  } else if (bid < 4 * HTOT + 320) {
    int rr = (bid - 4 * HTOT) * 4 + (threadIdx.x >> 6);
    int c = threadIdx.x & 63;
    int j_o = rr / HC, ch_o = rr % HC;
    float v = (c < j_o) ? W1[(size_t)(ch_o * NS + j_o) * NS + c] : 0.0f;
    W1p[(size_t)rr * NS + c] = (f16)v;
  } else {
    int i = bid - (4 * HTOT + 320);
    if (i < NS) {
      const float* src = W6 + (size_t)i * HTOT;
      for (int k = threadIdx.x; k < HTOT; k += 256) row[k] = src[k];
      __syncthreads();
      for (int xp = threadIdx.x; xp < HTOT; xp += 256) {
        int j_i = xp / HC, ch_i = xp % HC;
        float v = (j_i <= i) ? row[ch_i * NS + j_i] : 0.0f;
        W6p[(size_t)i * HTOT + xp] = (f16)v;
      }
    } else {
      for (int xp = threadIdx.x; xp < HTOT; xp += 256)
        W6p[(size_t)i * HTOT + xp] = (f16)0.0f;
    }
  }
}

// ---------------------------------------------------------------------------
// gemm_block_mfma: history GEMMs for block starting at spin I.
//  y = L in 0..3:  Zg[L][c][b]  = sum_{k<20I} Wp[L][20I+c][k] * AH[L][k][b], c<160
//  y = 4 (layer6): Zg6[t][b]    = sum_{k<20I} W6p[I+t][k]    * AH[4][k][b], t<8
// MFMA f32_16x16x32_f16; AH [L][g=k/8][b][e=k%8] is the raw B-fragment layout.
// I==0: G32=0 -> writes zeros (initializes Zg/Zg6; d_ws is poisoned each call).
// ---------------------------------------------------------------------------
__global__ __launch_bounds__(256) void gemm_block_mfma(
    const f16* __restrict__ Wp, const f16* __restrict__ W6p,
    const f16* __restrict__ AH, float* __restrict__ Zg,
    float* __restrict__ Zg6, int I, int BS) {
  const int L = blockIdx.y;
  const int w = threadIdx.x >> 6;
  const int l15 = threadIdx.x & 15;
  const int quad = (threadIdx.x & 63) >> 4;
  const int G32 = (HC * I) >> 5;

  if (L < 4) {
    const int wm = w & 1, wn = w >> 1;
    const int b0 = blockIdx.x * 64 + wn * 32;

    f32x4 acc[5][2];
#pragma unroll
    for (int mt = 0; mt < 5; ++mt) {
      acc[mt][0] = (f32x4){0.f, 0.f, 0.f, 0.f};
      acc[mt][1] = (f32x4){0.f, 0.f, 0.f, 0.f};
    }

    const f16* aptr = Wp + (size_t)(L * HTOT + HC * I + wm * 80 + l15) * HTOT + quad * 8;
    const f16* bptr = AH + ((size_t)(L * 160 + quad) * BS + b0 + l15) * 8;

    for (int ks = 0; ks < G32; ++ks) {
      f16x8 bf0 = *(const f16x8*)(bptr);
      f16x8 bf1 = *(const f16x8*)(bptr + 128);
      f16x8 af[5];
#pragma unroll
      for (int mt = 0; mt < 5; ++mt)
        af[mt] = *(const f16x8*)(aptr + (size_t)(mt * 16) * HTOT);
#pragma unroll
      for (int mt = 0; mt < 5; ++mt) {
        acc[mt][0] = __builtin_amdgcn_mfma_f32_16x16x32_f16(af[mt], bf0, acc[mt][0], 0, 0, 0);
        acc[mt][1] = __builtin_amdgcn_mfma_f32_16x16x32_f16(af[mt], bf1, acc[mt][1], 0, 0, 0);
      }
      aptr += 32;
      bptr += (size_t)4 * BS * 8;
    }

#pragma unroll
    for (int mt = 0; mt < 5; ++mt)
#pragma unroll
      for (int nt = 0; nt < 2; ++nt)
#pragma unroll
        for (int r = 0; r < 4; ++r) {
          int c = wm * 80 + mt * 16 + quad * 4 + r;
          int b = b0 + nt * 16 + l15;
          Zg[(size_t)(L * 160 + c) * BS + b] = acc[mt][nt][r];
        }
  } else {
    // layer-6 slice: M=16 tile over W6p rows I..I+15 (rows 8..15 discarded)
    const int b0 = blockIdx.x * 64 + w * 16;
    f32x4 acc = (f32x4){0.f, 0.f, 0.f, 0.f};
    const f16* aptr = W6p + (size_t)(I + l15) * HTOT + quad * 8;
    const f16* bptr = AH + ((size_t)(4 * 160 + quad) * BS + b0 + l15) * 8;
    for (int ks = 0; ks < G32; ++ks) {
      f16x8 af = *(const f16x8*)(aptr);
      f16x8 bf = *(const f16x8*)(bptr);
      acc = __builtin_amdgcn_mfma_f32_16x16x32_f16(af, bf, acc, 0, 0, 0);
      aptr += 32;
      bptr += (size_t)4 * BS * 8;
    }
#pragma unroll
    for (int r = 0; r < 4; ++r) {
      int c = quad * 4 + r;
      if (c < 8) Zg6[(size_t)c * BS + b0 + l15] = acc[r];
    }
  }
}

// ---------------------------------------------------------------------------
// seq_block v5: single-wave WG, 64 thr = 8 rows x 8 groups (3/3/3/3/2/2/2/2 ch).
// ALL inner loops compile-time-trip (full unroll): masked weights guarantee the
// padded terms contribute zero (W1p masks j>=i; Wp masks j_in>i; W6p masks
// j_in>I+tp; aL/sL tails zero-initialized). C2N templated: 10 for t<4, 20 for t>=4.
// ---------------------------------------------------------------------------
template <int C2N>
static __device__ __forceinline__ void seq_step(
    int t, int I, int r, int q, int nch, int ch0, int brel, int bg, int BS,
    const f16* __restrict__ Wp, const f16* __restrict__ W1p,
    const f16* __restrict__ W6p, const float* __restrict__ Zg,
    const float* __restrict__ u, float* __restrict__ outp,
    f16 (&aL)[5][BT][168], f16 (&sL)[BT][72], float (&z6r)[KB], int lane) {
  const int i = I + t;

  // ---- layer 1: full 8 chunks over sampled bits (W1p masks j >= i) ----
  {
    float acc[3] = {0, 0, 0};
#pragma unroll
    for (int c8 = 0; c8 < 8; ++c8) {
      f16x8 sv = *(const f16x8*)&sL[r][c8 * 8];
#pragma unroll
      for (int k = 0; k < 3; ++k) {
        f16x8 w = *(const f16x8*)(W1p + (size_t)(i * HC + ch0 + k) * NS + c8 * 8);
        acc[k] = dot8f(sv, w, acc[k]);
      }
    }
#pragma unroll
    for (int k = 0; k < 3; ++k)
      if (k < nch) aL[0][r][t * HC + ch0 + k] = (f16)sigm(acc[k]);
  }
  __syncthreads();

  // ---- layers 2..5: C2N fixed chunks; Zg(history) added at chain end ----
  float a5r[3];
#pragma unroll 1
  for (int L = 0; L < 4; ++L) {
    float zin[3];
#pragma unroll
    for (int k = 0; k < 3; ++k)
      zin[k] = Zg[(size_t)(L * 160 + t * HC + ch0 + k) * BS + brel];
    float z[3] = {0, 0, 0};
    const f16* wrow = Wp + ((size_t)(L * HTOT + i * HC + ch0)) * HTOT + HC * I;
#pragma unroll
    for (int c8 = 0; c8 < C2N; ++c8) {
      f16x8 av = *(const f16x8*)&aL[L][r][c8 * 8];
#pragma unroll
      for (int k = 0; k < 3; ++k) {
        f16x8 w = *(const f16x8*)(wrow + (size_t)k * HTOT + c8 * 8);
        z[k] = dot8f(av, w, z[k]);
      }
    }
#pragma unroll
    for (int k = 0; k < 3; ++k) {
      float a = sigm(zin[k] + z[k]);
      if (k < nch) aL[L + 1][r][t * HC + ch0 + k] = (f16)a;
      if (L == 3) a5r[k] = a;
    }
    __syncthreads();
  }

  // ---- scatter a5(spin i) into ALL z6 partials (W6p masks tp < t to zero) ----
#pragma unroll
  for (int tp = 0; tp < KB; ++tp) {
    float zz = z6r[tp];
#pragma unroll
    for (int k = 0; k < 3; ++k)
      if (k < nch)
        zz += (float)W6p[(size_t)(I + tp) * HTOT + i * HC + ch0 + k] * a5r[k];
    z6r[tp] = zz;
  }

  // ---- reduce z6 over 8 groups via shfl_xor; output + sample bit ----
  {
    float v = z6r[t];
    v += __shfl_xor(v, 8, 64);
    v += __shfl_xor(v, 16, 64);
    v += __shfl_xor(v, 32, 64);
    if (lane < BT) {
      float x = sigm(v);
      outp[(size_t)bg * NS + i] = x;  // final output col i == sampling-time x
      float uu = u[(size_t)i * NB + bg];
      sL[r][i] = (f16)((x >= uu) ? 1.0f : -1.0f);
    }
  }
  __syncthreads();
}

__global__ __launch_bounds__(64, 2) void seq_block(
    const f16* __restrict__ Wp, const f16* __restrict__ W1p,
    const f16* __restrict__ W6p, f16* __restrict__ AH,
    const float* __restrict__ Zg, const float* __restrict__ Zg6,
    f16* __restrict__ s_ws, const float* __restrict__ u,
    float* __restrict__ outp, int I, int BS, int b0) {
  __shared__ __align__(16) f16 aL[5][BT][168];   // 13440 B
  __shared__ __align__(16) f16 sL[BT][72];       // 1152 B  -> 14592 B total

  const int lane = threadIdx.x;
  const int r = lane & 7;
  const int q = lane >> 3;              // 0..7
  const int nch = (q < 4) ? 3 : 2;
  const int ch0 = (q < 4) ? 3 * q : 12 + 2 * (q - 4);
  const int brel = blockIdx.x * BT + r;
  const int bg = b0 + brel;

  // zero LDS activations / s (masked-weight tails must read as 0)
  {
    f16x8 z = {};
    f16x8* pa = (f16x8*)&aL[0][0][0];
    for (int k = lane; k < (5 * BT * 168) / 8; k += 64) pa[k] = z;
    f16x8* ps = (f16x8*)&sL[0][0];
    for (int k = lane; k < (BT * 72) / 8; k += 64) ps[k] = z;
  }
  __syncthreads();

  // load sampled-bit history j < I (I>>3 <= 7 chunks; group q loads chunk q)
  if (q < (I >> 3)) {
    f16x8 v = *(const f16x8*)(s_ws + (size_t)brel * NS + q * 8);
    *(f16x8*)&sL[r][q * 8] = v;
  }

  // layer-6 history from gemm: group q holds t=q's partial
  float z6r[KB];
#pragma unroll
  for (int t = 0; t < KB; ++t) z6r[t] = 0.0f;
  z6r[q] = Zg6[(size_t)q * BS + brel];
  __syncthreads();

#pragma unroll 1
  for (int t = 0; t < 4; ++t)
    seq_step<10>(t, I, r, q, nch, ch0, brel, bg, BS, Wp, W1p, W6p, Zg, u, outp,
                 aL, sL, z6r, lane);
#pragma unroll 1
  for (int t = 4; t < 8; ++t)
    seq_step<20>(t, I, r, q, nch, ch0, brel, bg, BS, Wp, W1p, W6p, Zg, u, outp,
                 aL, sL, z6r, lane);

  // ---- bulk writeout: block activations -> global AH ([L][g][b][e]), s bits ----
  for (int w = lane; w < 5 * 20 * BT; w += 64) {
    int rr = w & (BT - 1);
    int q8 = w >> 3;           // 0..99
    int L = q8 / 20, x8 = q8 % 20;
    f16x8 v = *(const f16x8*)&aL[L][rr][x8 * 8];
    int gg = ((HC * I) >> 3) + x8;
    *(f16x8*)(AH + ((size_t)(L * 160 + gg) * BS + blockIdx.x * BT + rr) * 8) = v;
  }
  if (lane < BT) {
    *(f16x8*)(s_ws + (size_t)(blockIdx.x * BT + lane) * NS + I) =
        *(const f16x8*)&sL[lane][I];
  }
}

// ---------------------------------------------------------------------------
extern "C" void kernel_launch(void* const* d_in, const int* in_sizes, int n_in,
                              void* d_out, int out_size, void* d_ws, size_t ws_size,
                              hipStream_t stream) {
  (void)in_sizes; (void)n_in; (void)out_size;
  const float* u  = (const float*)d_in[1];
  const float* W1 = (const float*)d_in[2];
  const float* W2 = (const float*)d_in[3];
  const float* W3 = (const float*)d_in[4];
  const float* W4 = (const float*)d_in[5];
  const float* W5 = (const float*)d_in[6];
  const float* W6 = (const float*)d_in[7];
  float* outp = (float*)d_out;

  const size_t wpEls  = (size_t)4 * HTOT * HTOT;   // 6,553,600
  const size_t w1Els  = (size_t)HTOT * NS;         // 81,920
  const size_t w6Els  = (size_t)W6R * HTOT;        // 102,400 (padded)
  const size_t wBytes = (wpEls + w1Els + w6Els) * sizeof(f16);
  // per-row: AH 5*160*8*2 + Zg 4*160*4 + Zg6 8*4 + s 64*2 = 15520 bytes
  size_t rem = (ws_size > wBytes + 4096) ? (ws_size - wBytes - 4096) : 0;
  long long bs = (long long)(rem / 15520);
  bs = (bs / 64) * 64;
  if (bs > NB) bs = NB;
  if (bs < 64) bs = 64;
  const int BS = (int)bs;

  f16* Wp  = (f16*)d_ws;
  f16* W1p = Wp + wpEls;
  f16* W6p = W1p + w1Els;
  f16* AH  = W6p + w6Els;                               // 5*160*BS*8 f16
  float* Zg  = (float*)(AH + (size_t)5 * 160 * BS * 8); // 4*160*BS f32
  float* Zg6 = Zg + (size_t)4 * 160 * BS;               // 8*BS f32
  f16* s_ws  = (f16*)(Zg6 + (size_t)8 * BS);            // BS*64 f16

  prep<<<dim3(4 * HTOT + 320 + W6R), dim3(256), 0, stream>>>(
      W1, W2, W3, W4, W5, W6, Wp, W1p, W6p);

  for (int c0 = 0; c0 < NB; c0 += BS) {
    int nr = NB - c0; if (nr > BS) nr = BS;
    for (int m = 0; m < NS / KB; ++m) {
      const int I = m * KB;
      gemm_block_mfma<<<dim3(nr / 64, 5), dim3(256), 0, stream>>>(
          Wp, W6p, AH, Zg, Zg6, I, BS);
      seq_block<<<dim3(nr / BT), dim3(64), 0, stream>>>(
          Wp, W1p, W6p, AH, Zg, Zg6, s_ws, u, outp, I, BS, c0);
    }
  }
}

// Round 7
// 1566.153 us; speedup vs baseline: 1.2653x; 1.2653x over previous
//
#include <hip/hip_runtime.h>

// Autoregressive masked net sampler:
//  - output col i == sampling-time x[:,i]  (masks: out i depends on spins < i only)
//  - spin blocks of KB=8: history part = dense MFMA GEMM, intra-block part =
//    per-row sequential — now ALSO MFMA (R7): one wave handles 16 batch rows,
//    each layer step = 2 M-tiles x 5 K-steps of 16x16x32_f16 off LDS B-frags.
// R6 lesson: dot8f full-unroll -> VGPR-bound load serialization + I$ bloat.
// R7: zero-padded A-weights (Wsq/W1sq) make all K trips compile-time with ~15
// loads + 10 MFMAs per layer (one latency exposure, ~2.4KB t-body).

#define NS   64          // spins
#define HC   20          // hidden channels per spin
#define HTOT 1280        // NS*HC
#define NB   16384       // batch
#define KB   8           // spins per block (8 blocks)
#define BT   16          // batch rows per seq workgroup (single wave: 16 x 4)
#define W6R  80          // W6p padded rows
#define ZGROWS (4*160 + 32)  // Zg rows + pad (seq's mt=1/quad>0 lanes read past 160)

typedef _Float16 f16;
typedef _Float16 f16x4 __attribute__((ext_vector_type(4)));
typedef _Float16 f16x8 __attribute__((ext_vector_type(8)));
typedef float f32x4 __attribute__((ext_vector_type(4)));

static __device__ __forceinline__ f32x4 mfma16(f16x8 a, f16x8 b, f32x4 c) {
  return __builtin_amdgcn_mfma_f32_16x16x32_f16(a, b, c, 0, 0, 0);
}

static __device__ __forceinline__ float sigm(float z) {
  return __builtin_amdgcn_rcpf(1.0f + __expf(-z));
}

// ---------------------------------------------------------------------------
// prep1: build masked, spin-major-permuted f16 weights (as R5).
//  Wp [L=0..3][cp][xp]  cp=j_o*20+ch_o, xp=j_i*20+ch_i, mask j_i <= j_o
//  W1p[cp][j_i]         mask j_i < j_o (exclusive)
//  W6p[i][xp]           mask j_i <= i (rows 64..79 zero)
// ---------------------------------------------------------------------------
__global__ __launch_bounds__(256) void prep1(
    const float* __restrict__ W1, const float* __restrict__ W2,
    const float* __restrict__ W3, const float* __restrict__ W4,
    const float* __restrict__ W5, const float* __restrict__ W6,
    f16* __restrict__ Wp, f16* __restrict__ W1p, f16* __restrict__ W6p) {
  __shared__ float row[HTOT];
  int bid = blockIdx.x;
  if (bid < 4 * HTOT) {
    int L = bid / HTOT, cp = bid % HTOT;
    int j_o = cp / HC, ch_o = cp % HC;
    const float* Wsrc = (L == 0) ? W2 : (L == 1) ? W3 : (L == 2) ? W4 : W5;
    const float* src = Wsrc + (size_t)(ch_o * NS + j_o) * HTOT;
    for (int k = threadIdx.x; k < HTOT; k += 256) row[k] = src[k];
    __syncthreads();
    f16* dst = Wp + (size_t)bid * HTOT;
    for (int xp = threadIdx.x; xp < HTOT; xp += 256) {
      int j_i = xp / HC, ch_i = xp % HC;
      float v = (j_i <= j_o) ? row[ch_i * NS + j_i] : 0.0f;
      dst[xp] = (f16)v;
    }
  } else if (bid < 4 * HTOT + 320) {
    int rr = (bid - 4 * HTOT) * 4 + (threadIdx.x >> 6);
    int c = threadIdx.x & 63;
    int j_o = rr / HC, ch_o = rr % HC;
    float v = (c < j_o) ? W1[(size_t)(ch_o * NS + j_o) * NS + c] : 0.0f;
    W1p[(size_t)rr * NS + c] = (f16)v;
  } else {
    int i = bid - (4 * HTOT + 320);
    if (i < NS) {
      const float* src = W6 + (size_t)i * HTOT;
      for (int k = threadIdx.x; k < HTOT; k += 256) row[k] = src[k];
      __syncthreads();
      for (int xp = threadIdx.x; xp < HTOT; xp += 256) {
        int j_i = xp / HC, ch_i = xp % HC;
        float v = (j_i <= i) ? row[ch_i * NS + j_i] : 0.0f;
        W6p[(size_t)i * HTOT + xp] = (f16)v;
      }
    } else {
      for (int xp = threadIdx.x; xp < HTOT; xp += 256)
        W6p[(size_t)i * HTOT + xp] = (f16)0.0f;
    }
  }
}

// ---------------------------------------------------------------------------
// prep2: seq A-operand repacks (from prep1 outputs; separate launch = ordered).
//  Wsq[L][i][chp<32][kk<160]: = chp<20 ? Wp[L][i*20+chp][(i/8)*160 + kk] : 0
//  W1sq[i][chp<32][j<64]:     = chp<20 ? W1p[i*20+chp][j] : 0
// Zero padding makes seq's fixed K/M trip counts mathematically exact.
// ---------------------------------------------------------------------------
__global__ __launch_bounds__(256) void prep2(
    const f16* __restrict__ Wp, const f16* __restrict__ W1p,
    f16* __restrict__ Wsq, f16* __restrict__ W1sq) {
  int bid = blockIdx.x;
  if (bid < 256) {
    int L = bid >> 6, i = bid & 63;
    const f16* src = Wp + ((size_t)L * HTOT + i * HC) * HTOT + (i >> 3) * 160;
    f16* dst = Wsq + (size_t)bid * 32 * 160;
    for (int el = threadIdx.x; el < 32 * 160; el += 256) {
      int chp = el / 160, kk = el % 160;
      dst[el] = (chp < HC) ? src[(size_t)chp * HTOT + kk] : (f16)0.0f;
    }
  } else {
    int i = bid - 256;
    const f16* src = W1p + (size_t)(i * HC) * NS;
    f16* dst = W1sq + (size_t)i * 32 * 64;
    for (int el = threadIdx.x; el < 32 * 64; el += 256) {
      int chp = el >> 6, j = el & 63;
      dst[el] = (chp < HC) ? src[(size_t)chp * NS + j] : (f16)0.0f;
    }
  }
}

// ---------------------------------------------------------------------------
// gemm_block_mfma: history GEMMs for block starting at spin I (unchanged R5).
//  y<4: Zg[L][c][b] = sum_{k<20I} Wp[L][20I+c][k] * AH[L][k][b]
//  y=4: Zg6[t][b]   = sum_{k<20I} W6p[I+t][k]    * AH[4][k][b]
// ---------------------------------------------------------------------------
__global__ __launch_bounds__(256) void gemm_block_mfma(
    const f16* __restrict__ Wp, const f16* __restrict__ W6p,
    const f16* __restrict__ AH, float* __restrict__ Zg,
    float* __restrict__ Zg6, int I, int BS) {
  const int L = blockIdx.y;
  const int w = threadIdx.x >> 6;
  const int l15 = threadIdx.x & 15;
  const int quad = (threadIdx.x & 63) >> 4;
  const int G32 = (HC * I) >> 5;

  if (L < 4) {
    const int wm = w & 1, wn = w >> 1;
    const int b0 = blockIdx.x * 64 + wn * 32;

    f32x4 acc[5][2];
#pragma unroll
    for (int mt = 0; mt < 5; ++mt) {
      acc[mt][0] = (f32x4){0.f, 0.f, 0.f, 0.f};
      acc[mt][1] = (f32x4){0.f, 0.f, 0.f, 0.f};
    }
    const f16* aptr = Wp + (size_t)(L * HTOT + HC * I + wm * 80 + l15) * HTOT + quad * 8;
    const f16* bptr = AH + ((size_t)(L * 160 + quad) * BS + b0 + l15) * 8;

    for (int ks = 0; ks < G32; ++ks) {
      f16x8 bf0 = *(const f16x8*)(bptr);
      f16x8 bf1 = *(const f16x8*)(bptr + 128);
      f16x8 af[5];
#pragma unroll
      for (int mt = 0; mt < 5; ++mt)
        af[mt] = *(const f16x8*)(aptr + (size_t)(mt * 16) * HTOT);
#pragma unroll
      for (int mt = 0; mt < 5; ++mt) {
        acc[mt][0] = mfma16(af[mt], bf0, acc[mt][0]);
        acc[mt][1] = mfma16(af[mt], bf1, acc[mt][1]);
      }
      aptr += 32;
      bptr += (size_t)4 * BS * 8;
    }
#pragma unroll
    for (int mt = 0; mt < 5; ++mt)
#pragma unroll
      for (int nt = 0; nt < 2; ++nt)
#pragma unroll
        for (int r = 0; r < 4; ++r) {
          int c = wm * 80 + mt * 16 + quad * 4 + r;
          int b = b0 + nt * 16 + l15;
          Zg[(size_t)(L * 160 + c) * BS + b] = acc[mt][nt][r];
        }
  } else {
    const int b0 = blockIdx.x * 64 + w * 16;
    f32x4 acc = (f32x4){0.f, 0.f, 0.f, 0.f};
    const f16* aptr = W6p + (size_t)(I + l15) * HTOT + quad * 8;
    const f16* bptr = AH + ((size_t)(4 * 160 + quad) * BS + b0 + l15) * 8;
    for (int ks = 0; ks < G32; ++ks) {
      f16x8 af = *(const f16x8*)(aptr);
      f16x8 bf = *(const f16x8*)(bptr);
      acc = mfma16(af, bf, acc);
      aptr += 32;
      bptr += (size_t)4 * BS * 8;
    }
#pragma unroll
    for (int r = 0; r < 4; ++r) {
      int c = quad * 4 + r;
      if (c < 8) Zg6[(size_t)c * BS + b0 + l15] = acc[r];
    }
  }
}

// ---------------------------------------------------------------------------
// seq_block v6 (MFMA, single wave, BT=16 rows):
// B-frag = aL[r=l15][k=quad*8] straight from LDS; A-frag = Wsq row (zero-padded
// masks make fixed 5 K-steps exact). D: m(ch)=quad*4+reg, n(row)=l15.
// Per t: L1 (2 Ksteps) -> L2..L5 (5 Ksteps each, +Zg at end) -> z6 (5 Ksteps
// off aL[4] vs W6p rows) -> sample. ~6 latency exposures per t.
// ---------------------------------------------------------------------------
__global__ __launch_bounds__(64, 1) void seq_block(
    const f16* __restrict__ Wsq, const f16* __restrict__ W1sq,
    const f16* __restrict__ W6p, f16* __restrict__ AH,
    const float* __restrict__ Zg, const float* __restrict__ Zg6,
    f16* __restrict__ s_ws, const float* __restrict__ u,
    float* __restrict__ outp, int I, int BS, int b0) {
  __shared__ __align__(16) f16 aL[5][BT][168];   // 26880 B (row 336B -> 2-way banks, free)
  __shared__ __align__(16) f16 sL[BT][72];       // 2304 B

  const int lane = threadIdx.x;
  const int l15 = lane & 15;
  const int quad = lane >> 4;
  const int r = l15;
  const int brel = blockIdx.x * BT + r;
  const int bg = b0 + brel;

  // zero LDS (unwritten regions must multiply as exact 0, and avoid stale NaN)
  {
    f16x8 z = {};
    f16x8* pa = (f16x8*)&aL[0][0][0];
    for (int k = lane; k < (5 * BT * 168) / 8; k += 64) pa[k] = z;
    f16x8* ps = (f16x8*)&sL[0][0];
    for (int k = lane; k < (BT * 72) / 8; k += 64) ps[k] = z;
  }
  __syncthreads();

  // sampled-bit history j < I
  {
    const int nck = I >> 3;
    for (int idx = lane; idx < BT * nck; idx += 64) {
      int rr = idx & 15, c8 = idx >> 4;
      *(f16x8*)&sL[rr][c8 * 8] =
          *(const f16x8*)(s_ws + (size_t)(blockIdx.x * BT + rr) * NS + c8 * 8);
    }
  }

  // prefetch z6 history + u thresholds (off critical path)
  float z6h[KB], uu[KB];
#pragma unroll
  for (int t = 0; t < KB; ++t) z6h[t] = Zg6[(size_t)t * BS + brel];
#pragma unroll
  for (int t = 0; t < KB; ++t) uu[t] = u[(size_t)(I + t) * NB + bg];
  __syncthreads();

#pragma unroll 1
  for (int t = 0; t < KB; ++t) {
    const int i = I + t;

    // ---- layer 1: A = W1sq[i] (2 M-tiles), B = sL (K=64, 2 K-steps) ----
    {
      const f16* a0 = W1sq + ((size_t)i * 32 + l15) * 64 + quad * 8;
      f16x8 b0v = *(const f16x8*)&sL[r][quad * 8];
      f16x8 b1v = *(const f16x8*)&sL[r][32 + quad * 8];
      f16x8 a00 = *(const f16x8*)(a0);
      f16x8 a01 = *(const f16x8*)(a0 + 32);
      f16x8 a10 = *(const f16x8*)(a0 + 16 * 64);
      f16x8 a11 = *(const f16x8*)(a0 + 16 * 64 + 32);
      f32x4 acc0 = {0.f, 0.f, 0.f, 0.f}, acc1 = {0.f, 0.f, 0.f, 0.f};
      acc0 = mfma16(a00, b0v, acc0);
      acc0 = mfma16(a01, b1v, acc0);
      acc1 = mfma16(a10, b0v, acc1);
      acc1 = mfma16(a11, b1v, acc1);
      f16x4 v0;
#pragma unroll
      for (int rg = 0; rg < 4; ++rg) v0[rg] = (f16)sigm(acc0[rg]);
      *(f16x4*)&aL[0][r][t * HC + quad * 4] = v0;
      if (quad == 0) {
        f16x4 v1;
#pragma unroll
        for (int rg = 0; rg < 4; ++rg) v1[rg] = (f16)sigm(acc1[rg]);
        *(f16x4*)&aL[0][r][t * HC + 16] = v1;
      }
    }
    __syncthreads();

    // ---- layers 2..5: A = Wsq[L][i], B = aL[L], + Zg history at chain end ----
#pragma unroll 1
    for (int L = 0; L < 4; ++L) {
      float zin[2][4];
#pragma unroll
      for (int mt = 0; mt < 2; ++mt)
#pragma unroll
        for (int rg = 0; rg < 4; ++rg)
          zin[mt][rg] =
              Zg[(size_t)(L * 160 + t * HC + mt * 16 + quad * 4 + rg) * BS + brel];
      const f16* abase = Wsq + (((size_t)L * 64 + i) * 32 + l15) * 160;
      const f16* lrow = &aL[L][r][0];
      f32x4 acc0 = {0.f, 0.f, 0.f, 0.f}, acc1 = {0.f, 0.f, 0.f, 0.f};
#pragma unroll
      for (int ks = 0; ks < 5; ++ks) {
        f16x8 bv = *(const f16x8*)(lrow + ks * 32 + quad * 8);
        f16x8 a0 = *(const f16x8*)(abase + ks * 32 + quad * 8);
        f16x8 a1 = *(const f16x8*)(abase + 16 * 160 + ks * 32 + quad * 8);
        acc0 = mfma16(a0, bv, acc0);
        acc1 = mfma16(a1, bv, acc1);
      }
      f16x4 v0;
#pragma unroll
      for (int rg = 0; rg < 4; ++rg) v0[rg] = (f16)sigm(zin[0][rg] + acc0[rg]);
      *(f16x4*)&aL[L + 1][r][t * HC + quad * 4] = v0;
      if (quad == 0) {
        f16x4 v1;
#pragma unroll
        for (int rg = 0; rg < 4; ++rg) v1[rg] = (f16)sigm(zin[1][rg] + acc1[rg]);
        *(f16x4*)&aL[L + 1][r][t * HC + 16] = v1;
      }
      __syncthreads();
    }

    // ---- z6 intra: A = W6p rows I+t.. (row m=0 is the one we need), B = aL[4] ----
    {
      const f16* w6b = W6p + (size_t)(i + l15) * HTOT + HC * I;
      const f16* l5 = &aL[4][r][0];
      f32x4 a6 = {0.f, 0.f, 0.f, 0.f};
#pragma unroll
      for (int ks = 0; ks < 5; ++ks) {
        f16x8 bv = *(const f16x8*)(l5 + ks * 32 + quad * 8);
        f16x8 av = *(const f16x8*)(w6b + ks * 32 + quad * 8);
        a6 = mfma16(av, bv, a6);
      }
      if (quad == 0) {  // D m=0 lives at quad=0, reg=0; n = l15 = r
        float x = sigm(a6[0] + z6h[t]);
        outp[(size_t)bg * NS + i] = x;  // final output col i == sampling-time x
        sL[r][i] = (f16)((x >= uu[t]) ? 1.0f : -1.0f);
      }
    }
    __syncthreads();
  }

  // ---- bulk writeout: aL -> AH ([L][g][b][e8]), sampled bits -> s_ws ----
  for (int w = lane; w < 5 * 20 * BT; w += 64) {
    int rr = w & 15;
    int q8 = w >> 4;
    int L = q8 / 20, x8 = q8 % 20;
    f16x8 v = *(const f16x8*)&aL[L][rr][x8 * 8];
    int gg = ((HC * I) >> 3) + x8;
    *(f16x8*)(AH + ((size_t)(L * 160 + gg) * BS + blockIdx.x * BT + rr) * 8) = v;
  }
  if (lane < BT) {
    *(f16x8*)(s_ws + (size_t)(blockIdx.x * BT + lane) * NS + I) =
        *(const f16x8*)&sL[lane][I];
  }
}

// ---------------------------------------------------------------------------
extern "C" void kernel_launch(void* const* d_in, const int* in_sizes, int n_in,
                              void* d_out, int out_size, void* d_ws, size_t ws_size,
                              hipStream_t stream) {
  (void)in_sizes; (void)n_in; (void)out_size;
  const float* u  = (const float*)d_in[1];
  const float* W1 = (const float*)d_in[2];
  const float* W2 = (const float*)d_in[3];
  const float* W3 = (const float*)d_in[4];
  const float* W4 = (const float*)d_in[5];
  const float* W5 = (const float*)d_in[6];
  const float* W6 = (const float*)d_in[7];
  float* outp = (float*)d_out;

  const size_t wpEls   = (size_t)4 * HTOT * HTOT;    // 6,553,600
  const size_t w1Els   = (size_t)HTOT * NS;          // 81,920
  const size_t w6Els   = (size_t)W6R * HTOT;         // 102,400
  const size_t wsqEls  = (size_t)4 * 64 * 32 * 160;  // 1,310,720
  const size_t w1sqEls = (size_t)64 * 32 * 64;       // 131,072
  const size_t wBytes = (wpEls + w1Els + w6Els + wsqEls + w1sqEls) * sizeof(f16);
  // per-row: AH 12800 + Zg(672 f32) 2688 + Zg6 32 + s 128 = 15648 bytes
  size_t rem = (ws_size > wBytes + 4096) ? (ws_size - wBytes - 4096) : 0;
  long long bs = (long long)(rem / 15648);
  bs = (bs / 64) * 64;
  if (bs > NB) bs = NB;
  if (bs < 64) bs = 64;
  const int BS = (int)bs;

  f16* Wp   = (f16*)d_ws;
  f16* W1p  = Wp + wpEls;
  f16* W6p  = W1p + w1Els;
  f16* Wsq  = W6p + w6Els;
  f16* W1sq = Wsq + wsqEls;
  f16* AH   = W1sq + w1sqEls;                           // 5*160*BS*8 f16
  float* Zg  = (float*)(AH + (size_t)5 * 160 * BS * 8); // ZGROWS*BS f32 (incl pad)
  float* Zg6 = Zg + (size_t)ZGROWS * BS;                // 8*BS f32
  f16* s_ws  = (f16*)(Zg6 + (size_t)8 * BS);            // BS*64 f16

  prep1<<<dim3(4 * HTOT + 320 + W6R), dim3(256), 0, stream>>>(
      W1, W2, W3, W4, W5, W6, Wp, W1p, W6p);
  prep2<<<dim3(256 + 64), dim3(256), 0, stream>>>(Wp, W1p, Wsq, W1sq);

  for (int c0 = 0; c0 < NB; c0 += BS) {
    int nr = NB - c0; if (nr > BS) nr = BS;
    for (int m = 0; m < NS / KB; ++m) {
      const int I = m * KB;
      gemm_block_mfma<<<dim3(nr / 64, 5), dim3(256), 0, stream>>>(
          Wp, W6p, AH, Zg, Zg6, I, BS);
      seq_block<<<dim3(nr / BT), dim3(64), 0, stream>>>(
          Wsq, W1sq, W6p, AH, Zg, Zg6, s_ws, u, outp, I, BS, c0);
    }
  }
}